// Round 12
// baseline (571.098 us; speedup 1.0000x reference)
//
#include <hip/hip_runtime.h>
#include <math.h>

// Problem constants
#define NTOK 16384   // B*L
#define LSEQ 4096
#define BATCH 4
#define DDIM 512
#define PDIM 128
#define VDIM 8
#define PI_F 3.14159265358979323846f

// scan chunking (round-11: doubled chunk counts for 2x block parallelism)
#define NC2 128           // chunks for (b,d) scans, chunk len 32
#define CL2 32
#define PL2 262144        // sum2 plane size = BATCH*DDIM*NC2
#define NC3 256           // chunks for kv scan, chunk len 16
#define CL3 16

// fused V|M|Q row stride (bf16 elements)
#define VMQ_S 1536

typedef __attribute__((ext_vector_type(8))) short bfrag8;
typedef __attribute__((ext_vector_type(4))) float facc4;

__device__ __forceinline__ float sigmoid_(float v) { return 1.0f / (1.0f + expf(-v)); }
__device__ __forceinline__ float gelu_(float v) { return 0.5f * v * (1.0f + erff(v * 0.70710678118654752f)); }

// bf16 helpers (raw ushort storage, RNE rounding)
__device__ __forceinline__ unsigned short f2bf(float f) {
    unsigned int u = __builtin_bit_cast(unsigned int, f);
    u += 0x7fffu + ((u >> 16) & 1u);
    return (unsigned short)(u >> 16);
}
__device__ __forceinline__ float bf2f(unsigned short h) {
    return __builtin_bit_cast(float, ((unsigned int)h) << 16);
}
__device__ __forceinline__ float bflo(unsigned int w) { return __builtin_bit_cast(float, w << 16); }
__device__ __forceinline__ float bfhi(unsigned int w) { return __builtin_bit_cast(float, w & 0xffff0000u); }

// async global->LDS, 16B per lane
__device__ __forceinline__ void async16(const unsigned short* g, unsigned short* l) {
    __builtin_amdgcn_global_load_lds(
        (const __attribute__((address_space(1))) unsigned int*)g,
        (__attribute__((address_space(3))) unsigned int*)l, 16, 0, 0);
}

// ---------------------------------------------------------------------------
// bf16 MFMA GEMM: 128x128 tile, BK=64, 4 waves (2x2), counted-vmcnt 2-buffer
// pipeline, slot-XOR swizzle (PMC-verified: 0 bank conflicts), XCD row-band
// swizzle (PMC-verified: FETCH = ideal). Round-9/10 text — FROZEN (PMC: t1
// 67.7-68.0 us, MfmaUtil ~19.5, VGPR 104). Do not modify.
// ---------------------------------------------------------------------------
__global__ __launch_bounds__(256) void gemm_bf16(
    const unsigned short* __restrict__ A, int ldA,
    const unsigned short* __restrict__ Wt,
    const float* __restrict__ bias, int K,
    float* __restrict__ Cf, unsigned short* __restrict__ Cb, int ldC, int colOff,
    const float* __restrict__ res, int ldRes,
    int act)
{
    __shared__ __align__(16) unsigned short Asm[2][128 * 64];
    __shared__ __align__(16) unsigned short Bsm[2][128 * 64];
    const int tid = threadIdx.x;
    const int lane = tid & 63;
    const int wv = tid >> 6;
    const int wm = wv & 1, wn = wv >> 1;
    const int quad = lane >> 4, cc = lane & 15;

    const int C = gridDim.x, R = gridDim.y;
    const int bid = blockIdx.x + C * blockIdx.y;
    const int xcd = bid & 7;
    const int s = bid >> 3;
    const int by = xcd * (R >> 3) + s / C;
    const int bx = s - (s / C) * C;
    const int row0 = by << 7;
    const int col0 = bx << 7;

    facc4 acc[4][4];
#pragma unroll
    for (int i = 0; i < 4; ++i)
#pragma unroll
        for (int j = 0; j < 4; ++j) acc[i][j] = (facc4){0.f, 0.f, 0.f, 0.f};

    const int nk = K >> 6;

    int srow[4]; int soff[4]; int sdst[4];
#pragma unroll
    for (int k = 0; k < 4; ++k) {
        int g = tid + k * 256;
        int r = g >> 3, sd = g & 7;
        srow[k] = r;
        soff[k] = (sd ^ (r & 7)) * 8;   // shorts
        sdst[k] = g * 8;                // shorts (linear LDS)
    }

    auto stage = [&](int t, int buf) {
        const int koff = t << 6;        // t*64 shorts
#pragma unroll
        for (int k = 0; k < 4; ++k) {
            async16(A  + (size_t)(row0 + srow[k]) * ldA + koff + soff[k], &Asm[buf][sdst[k]]);
            async16(Wt + (size_t)(col0 + srow[k]) * K   + koff + soff[k], &Bsm[buf][sdst[k]]);
        }
    };

    stage(0, 0);

    const int swz = cc & 7;
    int cur = 0;
    for (int t = 0; t < nk; ++t) {
        if (t + 1 < nk) {
            stage(t + 1, cur ^ 1);
            asm volatile("s_waitcnt vmcnt(8)" ::: "memory");
        } else {
            asm volatile("s_waitcnt vmcnt(0)" ::: "memory");
        }
        __builtin_amdgcn_s_barrier();
        __builtin_amdgcn_sched_barrier(0);
#pragma unroll
        for (int kk = 0; kk < 2; ++kk) {
            const int sl = ((kk * 4 + quad) ^ swz) * 8;
            bfrag8 afr[4], bfr[4];
#pragma unroll
            for (int mt = 0; mt < 4; ++mt)
                afr[mt] = *(const bfrag8*)&Asm[cur][(wm * 64 + mt * 16 + cc) * 64 + sl];
#pragma unroll
            for (int nt = 0; nt < 4; ++nt)
                bfr[nt] = *(const bfrag8*)&Bsm[cur][(wn * 64 + nt * 16 + cc) * 64 + sl];
#pragma unroll
            for (int mt = 0; mt < 4; ++mt)
#pragma unroll
                for (int nt = 0; nt < 4; ++nt)
                    acc[mt][nt] = __builtin_amdgcn_mfma_f32_16x16x32_bf16(
                        afr[mt], bfr[nt], acc[mt][nt], 0, 0, 0);
        }
        asm volatile("s_waitcnt lgkmcnt(0)" ::: "memory");
        __builtin_amdgcn_sched_barrier(0);   // rule #18 fence: nothing crosses the WAR point
        __builtin_amdgcn_s_barrier();
        cur ^= 1;
    }

#pragma unroll
    for (int nt = 0; nt < 4; ++nt) {
        int col = col0 + wn * 64 + nt * 16 + cc;
        float bvv = bias[col];
#pragma unroll
        for (int mt = 0; mt < 4; ++mt) {
            int rowb = row0 + wm * 64 + mt * 16 + quad * 4;
#pragma unroll
            for (int r = 0; r < 4; ++r) {
                float v = acc[mt][nt][r] + bvv;
                if (act == 1) v = gelu_(v);
                size_t row = (size_t)(rowb + r);
                if (res) v += res[row * ldRes + col];
                size_t idx = row * ldC + colOff + col;
                if (Cf) Cf[idx] = v;
                else    Cb[idx] = f2bf(v);
            }
        }
    }
}

// ---------------------------------------------------------------------------
// Fused prologue: phi tables + x->bf16 + ALL weight converts + bias pack in
// ONE launch. Segments:
//   [0,8192)      phi: cos/sin(pos_phases), 2097152 elems
//   [8192,12288)  xcvt: x fp32 -> XCAT left half bf16, 8/thread
//   [12288,15488) wcvt: 32x32 transpose tiles (table below)
//   [15488,15495) bias pack b_v|b_m|b_q|b_ke -> cbias (1664 floats)
// wcvt sub-table (wb = bid-12288):
//   [0,768)    w_v/w_m/w_q 512x512 -> WT + seg*262144  (contiguous 1536x512)
//   [768,832)  w_ke 512x128        -> WT + 786432
//   [832,1088) w_o  512x512        -> WT + 851968
//   [1088,1600) w_s1 1024x512      -> WT + 1114112
//   [1600,1664) w_s2 512x128       -> WT + 1638400
//   [1664,2688) w_t1 1024x1024     -> WT + 1703936
//   [2688,3200) w_t2 1024x512      -> WT + 2752512
// ---------------------------------------------------------------------------
__global__ __launch_bounds__(256) void k_prep(
    const float* __restrict__ pp, float* __restrict__ cphi, float* __restrict__ sphi,
    const float* __restrict__ x, unsigned short* __restrict__ xcat,
    const float* __restrict__ w_v, const float* __restrict__ w_m,
    const float* __restrict__ w_q, const float* __restrict__ w_o,
    const float* __restrict__ w_ke, const float* __restrict__ w_s1,
    const float* __restrict__ w_s2, const float* __restrict__ w_t1,
    const float* __restrict__ w_t2, unsigned short* __restrict__ WT,
    const float* __restrict__ b_v, const float* __restrict__ b_m,
    const float* __restrict__ b_q, const float* __restrict__ b_ke,
    float* __restrict__ cbias)
{
    const int bid = blockIdx.x;
    const int tid = threadIdx.x;
    if (bid < 8192) {
        int i = bid * 256 + tid;          // < 2097152 exactly
        float s, c;
        sincosf(pp[i], &s, &c);
        cphi[i] = c;
        sphi[i] = s;
        return;
    }
    if (bid < 12288) {
        int g = (bid - 8192) * 256 + tid; // 1,048,576 groups of 8
        int c8 = (g & 63) * 8, r = g >> 6;
        const float4* xp = (const float4*)(x + (size_t)r * 512 + c8);
        float4 a = xp[0], b = xp[1];
        uint4 o;
        o.x = (unsigned int)f2bf(a.x) | ((unsigned int)f2bf(a.y) << 16);
        o.y = (unsigned int)f2bf(a.z) | ((unsigned int)f2bf(a.w) << 16);
        o.z = (unsigned int)f2bf(b.x) | ((unsigned int)f2bf(b.y) << 16);
        o.w = (unsigned int)f2bf(b.z) | ((unsigned int)f2bf(b.w) << 16);
        *(uint4*)&xcat[(size_t)r * 1024 + c8] = o;
        return;
    }
    if (bid >= 15488) {
        int i = (bid - 15488) * 256 + tid;   // 0..1791, valid < 1664
        if (i < 512) cbias[i] = b_v[i];
        else if (i < 1024) cbias[i] = b_m[i - 512];
        else if (i < 1536) cbias[i] = b_q[i - 1024];
        else if (i < 1664) cbias[i] = b_ke[i - 1536];
        return;
    }
    const int wb = bid - 12288;
    const float* W; int K, N; unsigned short* Wt; int l;
    if (wb < 768) {
        K = 512; N = 512;
        int seg = wb >> 8; l = wb & 255;
        W = (seg == 0) ? w_v : (seg == 1) ? w_m : w_q;
        Wt = WT + seg * 262144;
    } else if (wb < 832)  { W = w_ke; K = 512;  N = 128;  Wt = WT + 786432;  l = wb - 768; }
    else if (wb < 1088)   { W = w_o;  K = 512;  N = 512;  Wt = WT + 851968;  l = wb - 832; }
    else if (wb < 1600)   { W = w_s1; K = 1024; N = 512;  Wt = WT + 1114112; l = wb - 1088; }
    else if (wb < 1664)   { W = w_s2; K = 512;  N = 128;  Wt = WT + 1638400; l = wb - 1600; }
    else if (wb < 2688)   { W = w_t1; K = 1024; N = 1024; Wt = WT + 1703936; l = wb - 1664; }
    else                  { W = w_t2; K = 1024; N = 512;  Wt = WT + 2752512; l = wb - 2688; }
    const int ntx = N >> 5;
    const int bx = l % ntx, by = l / ntx;
    __shared__ float t[32][33];
    const int tx = tid & 31, ty = tid >> 5;   // ty 0..7
#pragma unroll
    for (int r = 0; r < 4; ++r) {
        int k = by * 32 + ty + r * 8;
        t[ty + r * 8][tx] = W[(size_t)k * N + bx * 32 + tx];
    }
    __syncthreads();
#pragma unroll
    for (int r = 0; r < 4; ++r) {
        int n = bx * 32 + ty + r * 8;
        Wt[(size_t)n * K + by * 32 + tx] = f2bf(t[tx][ty + r * 8]);
    }
}

// ---------------------------------------------------------------------------
// Fused g_lin + values: one wave per row, x read ONCE coalesced.
// glin[r] = x[r,:]@w_g + b_g;  gv[r,m] = (x[r,:]@w_ve[:,m] + b_ve[m])*sigmoid(glin)
// ---------------------------------------------------------------------------
__global__ __launch_bounds__(256) void k_glinval(
    const float* __restrict__ x, const float* __restrict__ wg,
    const float* __restrict__ bg, const float* __restrict__ wve,
    const float* __restrict__ bve, float* __restrict__ glin,
    float* __restrict__ gv)
{
    int wid = threadIdx.x >> 6, lane = threadIdx.x & 63;
    int row = blockIdx.x * 4 + wid;
    const float4* xr = (const float4*)(x + (size_t)row * DDIM);
    const float4* w4 = (const float4*)wg;
    float4 a0 = xr[lane], a1 = xr[lane + 64];
    float4 w0 = w4[lane], w1 = w4[lane + 64];
    float p = a0.x * w0.x + a0.y * w0.y + a0.z * w0.z + a0.w * w0.w
            + a1.x * w1.x + a1.y * w1.y + a1.z * w1.z + a1.w * w1.w;
    float vm[8];
#pragma unroll
    for (int m = 0; m < 8; ++m) vm[m] = 0.f;
    const float4* wv4 = (const float4*)wve;
    float xa[8] = {a0.x, a0.y, a0.z, a0.w, a1.x, a1.y, a1.z, a1.w};
#pragma unroll
    for (int j = 0; j < 8; ++j) {
        int krow = (j < 4) ? (4 * lane + j) : (256 + 4 * lane + (j - 4));
        float4 wlo = wv4[krow * 2], whi = wv4[krow * 2 + 1];
        float xv = xa[j];
        vm[0] += xv * wlo.x; vm[1] += xv * wlo.y; vm[2] += xv * wlo.z; vm[3] += xv * wlo.w;
        vm[4] += xv * whi.x; vm[5] += xv * whi.y; vm[6] += xv * whi.z; vm[7] += xv * whi.w;
    }
#pragma unroll
    for (int d = 32; d >= 1; d >>= 1) {
        p += __shfl_xor(p, d, 64);
#pragma unroll
        for (int m = 0; m < 8; ++m) vm[m] += __shfl_xor(vm[m], d, 64);
    }
    if (lane == 0) {
        float gl = p + bg[0];
        glin[row] = gl;
        float sg = sigmoid_(gl);
        float* gp = gv + (size_t)row * VDIM;
#pragma unroll
        for (int m = 0; m < 8; ++m) gp[m] = (vm[m] + bve[m]) * sg;
    }
}

// ---------------------------------------------------------------------------
// scan family 1: per (b,d) cumsums of {wv*cos, wv*sin, mag, x} — 3 passes
// v1/mlin/qlin live row-interleaved in VMQ (stride 1536, offsets 0/512/1024).
// NC2=128 chunks (1024 blocks = 4/CU) for latency hiding.
// ---------------------------------------------------------------------------
__global__ __launch_bounds__(256) void k_scan1a(
    const unsigned short* __restrict__ vmq, const float* __restrict__ x,
    const float* __restrict__ cphi, const float* __restrict__ sphi,
    const float* __restrict__ msp, float* __restrict__ sum2)
{
    int g = blockIdx.x * 256 + threadIdx.x;   // B*NC2*D = 262144
    int d = g & 511;
    int rest = g >> 9;
    int chunk = rest & (NC2 - 1);
    int b = rest >> 7;
    float msabs = fabsf(msp[0]);
    size_t row = (size_t)b * LSEQ + chunk * CL2;
    const unsigned short* vp = vmq + row * VMQ_S + d;
    const float* xp = x + row * DDIM + d;
    size_t pbase = ((size_t)chunk * CL2) * DDIM + d;
    float ac = 0.f, as = 0.f, am = 0.f, ax = 0.f;
    for (int i = 0; i < CL2; ++i) {
        float vv = bf2f(vp[0]);
        float ml = bf2f(vp[512]);
        float xv = xp[0];
        float cp = cphi[pbase], sp = sphi[pbase];
        float mag = msabs * sigmoid_(ml);
        float wv = mag * vv;
        ac += wv * cp; as += wv * sp; am += mag; ax += xv;
        vp += VMQ_S; xp += DDIM; pbase += DDIM;
    }
    int col = (b * DDIM + d) * NC2 + chunk;   // [b][d][chunk]
    sum2[0 * PL2 + col] = ac;
    sum2[1 * PL2 + col] = as;
    sum2[2 * PL2 + col] = am;
    sum2[3 * PL2 + col] = ax;
}

__global__ __launch_bounds__(256) void k_scan1b(float* __restrict__ sum2)
{
    int g = blockIdx.x * 256 + threadIdx.x;   // 4*B*D = 8192 rows of NC2
    float* p = sum2 + (size_t)g * NC2;
    float run = 0.f;
    for (int i = 0; i < NC2; ++i) { float t = p[i]; p[i] = run; run += t; }
}

__global__ __launch_bounds__(256) void k_scan1c(
    const unsigned short* __restrict__ vmq, const float* __restrict__ x,
    const float* __restrict__ cphi, const float* __restrict__ sphi,
    const float* __restrict__ msp, const float* __restrict__ sum2,
    unsigned short* __restrict__ pret, unsigned short* __restrict__ xcat)
{
    int g = blockIdx.x * 256 + threadIdx.x;
    int d = g & 511;
    int rest = g >> 9;
    int chunk = rest & (NC2 - 1);
    int b = rest >> 7;
    float msabs = fabsf(msp[0]);
    int col = (b * DDIM + d) * NC2 + chunk;
    float ac = sum2[col];
    float as = sum2[PL2 + col];
    float am = sum2[2 * PL2 + col];
    float ax = sum2[3 * PL2 + col];
    size_t row = (size_t)b * LSEQ + chunk * CL2;
    const unsigned short* vp = vmq + row * VMQ_S + d;
    size_t base = row * DDIM + d;
    size_t pbase = ((size_t)chunk * CL2) * DDIM + d;
    int l = chunk * CL2;
    const float rsd = 0.04419417382415922f;   // 1/sqrt(512)
    for (int i = 0; i < CL2; ++i, ++l) {
        float vv = bf2f(vp[0]);
        float ml = bf2f(vp[512]);
        float q = bf2f(vp[1024]);
        float xv = x[base];
        float cp = cphi[pbase], sp = sphi[pbase];
        float mag = msabs * sigmoid_(ml);
        float wv = mag * vv;
        ac += wv * cp; as += wv * sp; am += mag; ax += xv;
        float inv = rsqrtf(am + 1e-8f);
        float mc = ac * inv, msn = as * inv;
        float cq, sq;
        sincosf(q, &sq, &cq);
        float cpq = cp * cq - sp * sq;   // cos(phi+q)
        float spq = sp * cq + cp * sq;   // sin(phi+q)
        pret[base] = f2bf((mc * cpq + msn * spq) * rsd);
        size_t orow = (size_t)b * LSEQ + l;
        xcat[orow * 1024 + 512 + d] = f2bf(ax / (float)(l + 1));
        vp += VMQ_S; base += DDIM; pbase += DDIM;
    }
}

// ---------------------------------------------------------------------------
// phase tables (bf16): storage_phase (from sk fp32) and query_phase (ke bf16)
// ---------------------------------------------------------------------------
__global__ void k_phases(const float* __restrict__ sk, const unsigned short* __restrict__ ke,
                         unsigned short* __restrict__ csp, unsigned short* __restrict__ ssp,
                         unsigned short* __restrict__ cqp, unsigned short* __restrict__ sqp, int n)
{
    int g = blockIdx.x * 256 + threadIdx.x;
    if (g < n) {
        float s, c;
        float spv = tanhf(sk[g]) * PI_F;
        sincosf(spv, &s, &c);
        csp[g] = f2bf(c); ssp[g] = f2bf(s);
        float qpv = tanhf(bf2f(ke[g])) * PI_F;
        sincosf(qpv, &s, &c);
        cqp[g] = f2bf(c); sqp[g] = f2bf(s);
    }
}

// ---------------------------------------------------------------------------
// gate cumsum per batch: block-parallel scan of sigmoid(g_lin) over L=4096
// ---------------------------------------------------------------------------
__global__ __launch_bounds__(1024) void k_gatescan(const float* __restrict__ glin,
                                                   float* __restrict__ gcum)
{
    __shared__ float s[1024];
    int b = blockIdx.x, tid = threadIdx.x;
    const float* gp = glin + (size_t)b * LSEQ + tid * 4;
    float e0 = sigmoid_(gp[0]);
    float e1 = sigmoid_(gp[1]);
    float e2 = sigmoid_(gp[2]);
    float e3 = sigmoid_(gp[3]);
    float l0 = e0, l1 = l0 + e1, l2 = l1 + e2, l3 = l2 + e3;
    s[tid] = l3;
    __syncthreads();
    for (int off = 1; off < 1024; off <<= 1) {
        float t = (tid >= off) ? s[tid - off] : 0.0f;
        __syncthreads();
        s[tid] += t;
        __syncthreads();
    }
    float excl = s[tid] - l3;
    float* out = gcum + (size_t)b * LSEQ + tid * 4;
    out[0] = excl + l0; out[1] = excl + l1; out[2] = excl + l2; out[3] = excl + l3;
}

// ---------------------------------------------------------------------------
// kv scan: state (P,V) per batch. Block = (b, chunk). Wave w owns v in
// {2w,2w+1}; lane owns 4 consecutive p. sum3 layout: [b][p][v][cs][chunk].
// NC3=256 chunks (1024 blocks = 4/CU). Phase tables bf16 (L2-resident).
// ---------------------------------------------------------------------------
__device__ __forceinline__ size_t kv_sum_idx(int b, int p, int v) {
    return ((((size_t)b * PDIM + p) * VDIM + v) * 2) * NC3;
}

__global__ __launch_bounds__(256) void k_kv1(const unsigned short* __restrict__ csp,
                                             const unsigned short* __restrict__ ssp,
                                             const float* __restrict__ gv,
                                             float* __restrict__ sum3)
{
    int blk = blockIdx.x;                 // B*NC3 = 1024
    int chunk = blk & (NC3 - 1), b = blk >> 8;
    int tid = threadIdx.x;
    int w = tid >> 6, lane = tid & 63;
    int v = 2 * w + (lane & 1);
    int pq = lane >> 1;                   // 0..31
    float sc[4] = {0, 0, 0, 0}, ss[4] = {0, 0, 0, 0};
    const uint2* c2p = (const uint2*)csp;
    const uint2* s2p = (const uint2*)ssp;
    int t = b * LSEQ + chunk * CL3;
    for (int i = 0; i < CL3; ++i, ++t) {
        uint2 cu = c2p[(size_t)t * 32 + pq];
        uint2 su = s2p[(size_t)t * 32 + pq];
        float g = gv[(size_t)t * VDIM + v];
        sc[0] += bflo(cu.x) * g; sc[1] += bfhi(cu.x) * g;
        sc[2] += bflo(cu.y) * g; sc[3] += bfhi(cu.y) * g;
        ss[0] += bflo(su.x) * g; ss[1] += bfhi(su.x) * g;
        ss[2] += bflo(su.y) * g; ss[3] += bfhi(su.y) * g;
    }
#pragma unroll
    for (int j = 0; j < 4; ++j) {
        size_t base = kv_sum_idx(b, pq * 4 + j, v) + chunk;
        sum3[base] = sc[j];
        sum3[base + NC3] = ss[j];
    }
}

__global__ __launch_bounds__(256) void k_kv2(float* __restrict__ sum3)
{
    int g = blockIdx.x * 256 + threadIdx.x;   // B*P*V*2 = 8192 rows
    float* p = sum3 + (size_t)g * NC3;
    float run = 0.f;
    for (int i = 0; i < NC3; ++i) { float t = p[i]; p[i] = run; run += t; }
}

__global__ __launch_bounds__(256) void k_kv3(const unsigned short* __restrict__ csp,
                                             const unsigned short* __restrict__ ssp,
                                             const unsigned short* __restrict__ cqp,
                                             const unsigned short* __restrict__ sqp,
                                             const float* __restrict__ gv,
                                             const float* __restrict__ gcum,
                                             const float* __restrict__ sum3,
                                             float* __restrict__ kvr)
{
    int blk = blockIdx.x;
    int chunk = blk & (NC3 - 1), b = blk >> 8;
    int tid = threadIdx.x;
    int w = tid >> 6, lane = tid & 63;
    int v = 2 * w + (lane & 1);
    int pq = lane >> 1;
    float sc[4], ss[4];
#pragma unroll
    for (int j = 0; j < 4; ++j) {
        size_t base = kv_sum_idx(b, pq * 4 + j, v) + chunk;
        sc[j] = sum3[base];
        ss[j] = sum3[base + NC3];
    }
    const uint2* c2p = (const uint2*)csp;
    const uint2* s2p = (const uint2*)ssp;
    const uint2* cq2p = (const uint2*)cqp;
    const uint2* sq2p = (const uint2*)sqp;
    const float rsp = 0.08838834764831845f;   // 1/sqrt(128)
    int t = b * LSEQ + chunk * CL3;
    for (int i = 0; i < CL3; ++i, ++t) {
        uint2 cu = c2p[(size_t)t * 32 + pq];
        uint2 su = s2p[(size_t)t * 32 + pq];
        float g = gv[(size_t)t * VDIM + v];
        sc[0] += bflo(cu.x) * g; sc[1] += bfhi(cu.x) * g;
        sc[2] += bflo(cu.y) * g; sc[3] += bfhi(cu.y) * g;
        ss[0] += bflo(su.x) * g; ss[1] += bfhi(su.x) * g;
        ss[2] += bflo(su.y) * g; ss[3] += bfhi(su.y) * g;
        uint2 qcu = cq2p[(size_t)t * 32 + pq];
        uint2 qsu = sq2p[(size_t)t * 32 + pq];
        float part = bflo(qcu.x) * sc[0] + bfhi(qcu.x) * sc[1]
                   + bflo(qcu.y) * sc[2] + bfhi(qcu.y) * sc[3]
                   + bflo(qsu.x) * ss[0] + bfhi(qsu.x) * ss[1]
                   + bflo(qsu.y) * ss[2] + bfhi(qsu.y) * ss[3];
        part += __shfl_down(part, 32, 64);
        part += __shfl_down(part, 16, 64);
        part += __shfl_down(part, 8, 64);
        part += __shfl_down(part, 4, 64);
        part += __shfl_down(part, 2, 64);
        if (lane < 2) {
            float gc = gcum[t];
            float scale = rsqrtf(fmaxf(gc, 1.0f)) * rsp;
            kvr[(size_t)t * VDIM + v] = part * scale;
        }
    }
}

// ---------------------------------------------------------------------------
// Fused kv_out + LayerNorm: one wave per row. Reads COMB left half (written
// by o-gemm), computes right half = kvr@w_kv + b_kv in-register, LayerNorms
// the full 1024 row, writes both halves bf16 in place.
// ---------------------------------------------------------------------------
__global__ __launch_bounds__(256) void k_kvln(unsigned short* __restrict__ comb,
                                              const float* __restrict__ kvr,
                                              const float* __restrict__ wkv,
                                              const float* __restrict__ bkv,
                                              const float* __restrict__ gam,
                                              const float* __restrict__ bet)
{
    int wid = threadIdx.x >> 6, lane = threadIdx.x & 63;
    int row = blockIdx.x * 4 + wid;
    unsigned int* rp = (unsigned int*)(comb + (size_t)row * 1024);
    // left half: 8 bf16 at cols [8*lane, 8*lane+8)
    uint4 uL = *(uint4*)&rp[lane * 4];
    float vl[8];
    vl[0] = bflo(uL.x); vl[1] = bfhi(uL.x); vl[2] = bflo(uL.y); vl[3] = bfhi(uL.y);
    vl[4] = bflo(uL.z); vl[5] = bfhi(uL.z); vl[6] = bflo(uL.w); vl[7] = bfhi(uL.w);
    // right half: kvout for wkv cols [8*lane, 8*lane+8)
    const float* kr = kvr + (size_t)row * VDIM;
    float k0 = kr[0], k1 = kr[1], k2 = kr[2], k3 = kr[3];
    float k4 = kr[4], k5 = kr[5], k6 = kr[6], k7 = kr[7];
    int c0 = lane * 8;
    float vr[8];
#pragma unroll
    for (int j = 0; j < 8; ++j) {
        int c = c0 + j;
        vr[j] = bkv[c]
              + k0 * wkv[0 * DDIM + c] + k1 * wkv[1 * DDIM + c]
              + k2 * wkv[2 * DDIM + c] + k3 * wkv[3 * DDIM + c]
              + k4 * wkv[4 * DDIM + c] + k5 * wkv[5 * DDIM + c]
              + k6 * wkv[6 * DDIM + c] + k7 * wkv[7 * DDIM + c];
    }
    float s = 0.f, s2 = 0.f;
#pragma unroll
    for (int j = 0; j < 8; ++j) {
        s += vl[j] + vr[j];
        s2 += vl[j] * vl[j] + vr[j] * vr[j];
    }
    for (int m = 32; m >= 1; m >>= 1) {
        s += __shfl_xor(s, m, 64);
        s2 += __shfl_xor(s2, m, 64);
    }
    float mu = s * (1.0f / 1024.0f);
    float var = s2 * (1.0f / 1024.0f) - mu * mu;
    float inv = rsqrtf(var + 1e-5f);
    unsigned int oL[4], oR[4];
#pragma unroll
    for (int jj = 0; jj < 4; ++jj) {
        float l0 = (vl[2 * jj] - mu) * inv * gam[c0 + 2 * jj] + bet[c0 + 2 * jj];
        float l1 = (vl[2 * jj + 1] - mu) * inv * gam[c0 + 2 * jj + 1] + bet[c0 + 2 * jj + 1];
        oL[jj] = (unsigned int)f2bf(l0) | ((unsigned int)f2bf(l1) << 16);
        int rc = 512 + c0 + 2 * jj;
        float r0 = (vr[2 * jj] - mu) * inv * gam[rc] + bet[rc];
        float r1 = (vr[2 * jj + 1] - mu) * inv * gam[rc + 1] + bet[rc + 1];
        oR[jj] = (unsigned int)f2bf(r0) | ((unsigned int)f2bf(r1) << 16);
    }
    *(uint4*)&rp[lane * 4] = make_uint4(oL[0], oL[1], oL[2], oL[3]);
    *(uint4*)&rp[256 + lane * 4] = make_uint4(oR[0], oR[1], oR[2], oR[3]);
}

// ---------------------------------------------------------------------------
extern "C" void kernel_launch(void* const* d_in, const int* in_sizes, int n_in,
                              void* d_out, int out_size, void* d_ws, size_t ws_size,
                              hipStream_t stream)
{
    const float* x    = (const float*)d_in[0];
    const float* pp   = (const float*)d_in[1];
    const float* msp  = (const float*)d_in[2];
    const float* w_v  = (const float*)d_in[3];
    const float* b_v  = (const float*)d_in[4];
    const float* w_o  = (const float*)d_in[5];
    const float* b_o  = (const float*)d_in[6];
    const float* w_m  = (const float*)d_in[7];
    const float* b_m  = (const float*)d_in[8];
    const float* w_q  = (const float*)d_in[9];
    const float* b_q  = (const float*)d_in[10];
    const float* w_ke = (const float*)d_in[11];
    const float* b_ke = (const float*)d_in[12];
    const float* w_ve = (const float*)d_in[13];
    const float* b_ve = (const float*)d_in[14];
    const float* w_s1 = (const float*)d_in[15];
    const float* b_s1 = (const float*)d_in[16];
    const float* w_s2 = (const float*)d_in[17];
    const float* b_s2 = (const float*)d_in[18];
    const float* w_g  = (const float*)d_in[19];
    const float* b_g  = (const float*)d_in[20];
    const float* w_kv = (const float*)d_in[21];
    const float* b_kv = (const float*)d_in[22];
    const float* ln_g = (const float*)d_in[23];
    const float* ln_b = (const float*)d_in[24];
    const float* w_t1 = (const float*)d_in[25];
    const float* b_t1 = (const float*)d_in[26];
    const float* w_t2 = (const float*)d_in[27];
    const float* b_t2 = (const float*)d_in[28];
    float* out = (float*)d_out;
    float* ws = (float*)d_ws;
    (void)ws_size; (void)n_in; (void)in_sizes; (void)out_size;

    // ---- workspace layout (float offsets)
    // Lifetime-overlap notes for the enlarged scan buffers:
    //   SUM2 [13795328,14843904): live scan1a..scan1c; overlaps old SUM3 head
    //     (SUM3 written first at kv1, after scan1c) — disjoint lifetimes.
    //   SUM3 [14319616,16416768): live kv1..kv3; overlaps SUM2 tail (dead) and
    //     HSbf head (dead after s2 gemm, which precedes kv1).
    //   KVRb  [16416768,16547840): written kv3, read kvln; inside dead HS region.
    unsigned short* VMQ    = (unsigned short*)(ws);              // N*1536 bf16 [dead after scan1c]
    float*          SKf    = ws + 4194304;                       // N*P fp32, inside dead VMQ region [alive step4->5]
    unsigned short* CSP    = (unsigned short*)(ws + 8388608);    // 4 bf16 phase tables reuse VMQ upper part
    unsigned short* SSP    = CSP + 2097152;
    unsigned short* CQP    = CSP + 2 * 2097152;
    unsigned short* SQP    = CSP + 3 * 2097152;
    unsigned short* KEbf   = (unsigned short*)(ws + 12582912);   // N*P bf16
    float* GVb   = ws + 13631488;                                // N*V
    float* GLINb = ws + 13762560;                                // N
    float* GCUMb = ws + 13778944;                                // N
    float* SUM2b = ws + 13795328;                                // 4*PL2 = 1048576
    float* CBIAS = SUM2b;                                        // 1664 floats, live only until VMQ gemm done
    float* SUM3b = ws + 14319616;                                // 2097152 (see lifetime notes)
    float* KVRb  = ws + 16416768;                                // N*V (inside dead HS region at kv3 time)
    float* CPHIb = ws + 15499264;                                // L*D fp32 [dead after scan1c]
    float* SPHIb = ws + 17596416;                                // L*D fp32 [dead after scan1c]
    unsigned short* HSbf   = (unsigned short*)(ws + 15499264);   // N*D bf16, reuses CPHI+SPHI (written step 4, dead after s2)
    unsigned short* PRETbf = (unsigned short*)(ws + 19693568);   // N*D bf16 [dead after o-gemm]
    unsigned short* XCAT   = (unsigned short*)(ws + 23887872);   // N*1024 bf16 [dead after s1]
    unsigned short* COMBbf = XCAT;                               // N*1024 bf16, reuses XCAT
    unsigned short* HTbf   = (unsigned short*)(ws);              // N*1024 bf16, reuses VMQ/SK
    unsigned short* WT     = (unsigned short*)(ws + 32276480);
    unsigned short* wv_t  = WT;                  // [wv|wm|wq] contiguous: 1536 x 512
    unsigned short* wke_t = WT + 786432;         // 128x512
    unsigned short* wo_t  = WT + 851968;         // 512x512
    unsigned short* ws1_t = WT + 1114112;        // 512x1024
    unsigned short* ws2_t = WT + 1638400;        // 128x512
    unsigned short* wt1_t = WT + 1703936;        // 1024x1024
    unsigned short* wt2_t = WT + 2752512;        // 512x1024

    // 1. fused prologue: phi tables + x conversion + all weight converts + bias
    k_prep<<<15495, 256, 0, stream>>>(pp, CPHIb, SPHIb, x, XCAT,
                                      w_v, w_m, w_q, w_o, w_ke, w_s1, w_s2,
                                      w_t1, w_t2, WT, b_v, b_m, b_q, b_ke, CBIAS);

    // 2. token GEMMs on x. V/M/Q fused (N=1536); KE separate.
    gemm_bf16<<<dim3(12, 128), 256, 0, stream>>>(XCAT, 1024, wv_t, CBIAS, 512, nullptr, VMQ, VMQ_S, 0, nullptr, 0, 0);
    gemm_bf16<<<dim3(1, 128), 256, 0, stream>>>(XCAT, 1024, wke_t, b_ke, 512, nullptr, KEbf, 128, 0, nullptr, 0, 0);
    k_glinval<<<4096, 256, 0, stream>>>(x, w_g, b_g, w_ve, b_ve, GLINb, GVb);

    // 3. (b,d) scans -> pos_ret (bf16), context_avg (bf16 into XCAT right half)
    k_scan1a<<<1024, 256, 0, stream>>>(VMQ, x, CPHIb, SPHIb, msp, SUM2b);
    k_scan1b<<<32, 256, 0, stream>>>(SUM2b);
    k_scan1c<<<1024, 256, 0, stream>>>(VMQ, x, CPHIb, SPHIb, msp, SUM2b, PRETbf, XCAT);

    // 4. storage-key branch: s1 (XCAT) -> gelu -> bf16 hs; s2 -> fp32 sk
    gemm_bf16<<<dim3(4, 128), 256, 0, stream>>>(XCAT, 1024, ws1_t, b_s1, 1024, nullptr, HSbf, 512, 0, nullptr, 0, 1);
    gemm_bf16<<<dim3(1, 128), 256, 0, stream>>>(HSbf, 512, ws2_t, b_s2, 512, SKf, nullptr, 128, 0, nullptr, 0, 0);

    // 5. phase tables (bf16) for storage/query; gate cumsum
    k_phases<<<8192, 256, 0, stream>>>(SKf, KEbf, CSP, SSP, CQP, SQP, 2097152);
    k_gatescan<<<4, 1024, 0, stream>>>(GLINb, GCUMb);

    // 6. kv scan -> kv_retrieved (fp32)
    k_kv1<<<1024, 256, 0, stream>>>(CSP, SSP, GVb, SUM3b);
    k_kv2<<<32, 256, 0, stream>>>(SUM3b);
    k_kv3<<<1024, 256, 0, stream>>>(CSP, SSP, CQP, SQP, GVb, GCUMb, SUM3b, KVRb);

    // 7. heads into combined (bf16), fused kvout+LN, MLP (bf16), residual fp32
    gemm_bf16<<<dim3(4, 128), 256, 0, stream>>>(PRETbf, 512, wo_t, b_o, 512, nullptr, COMBbf, 1024, 0, nullptr, 0, 0);
    k_kvln<<<4096, 256, 0, stream>>>(COMBbf, KVRb, w_kv, b_kv, ln_g, ln_b);
    gemm_bf16<<<dim3(8, 128), 256, 0, stream>>>(COMBbf, 1024, wt1_t, b_t1, 1024, nullptr, HTbf, 1024, 0, nullptr, 0, 1);
    gemm_bf16<<<dim3(4, 128), 256, 0, stream>>>(HTbf, 1024, wt2_t, b_t2, 1024, out, nullptr, 512, 0, x, 512, 0);
}

// Round 13
// 556.568 us; speedup vs baseline: 1.0261x; 1.0261x over previous
//
#include <hip/hip_runtime.h>
#include <math.h>

// Problem constants
#define NTOK 16384   // B*L
#define LSEQ 4096
#define BATCH 4
#define DDIM 512
#define PDIM 128
#define VDIM 8
#define PI_F 3.14159265358979323846f

// scan chunking (round-10 verified optimum: fewer, longer chunks)
#define NC2 64            // chunks for (b,d) scans, chunk len 64
#define CL2 64
#define PL2 131072        // sum2 plane size = BATCH*DDIM*NC2
#define NC3 128           // chunks for kv scan, chunk len 32
#define CL3 32

// fused V|M|Q row stride (bf16 elements)
#define VMQ_S 1536

typedef __attribute__((ext_vector_type(8))) short bfrag8;
typedef __attribute__((ext_vector_type(4))) float facc4;

__device__ __forceinline__ float sigmoid_(float v) { return 1.0f / (1.0f + expf(-v)); }
__device__ __forceinline__ float gelu_(float v) { return 0.5f * v * (1.0f + erff(v * 0.70710678118654752f)); }

// bf16 helpers (raw ushort storage, RNE rounding)
__device__ __forceinline__ unsigned short f2bf(float f) {
    unsigned int u = __builtin_bit_cast(unsigned int, f);
    u += 0x7fffu + ((u >> 16) & 1u);
    return (unsigned short)(u >> 16);
}
__device__ __forceinline__ float bf2f(unsigned short h) {
    return __builtin_bit_cast(float, ((unsigned int)h) << 16);
}
__device__ __forceinline__ float bflo(unsigned int w) { return __builtin_bit_cast(float, w << 16); }
__device__ __forceinline__ float bfhi(unsigned int w) { return __builtin_bit_cast(float, w & 0xffff0000u); }

// async global->LDS, 16B per lane
__device__ __forceinline__ void async16(const unsigned short* g, unsigned short* l) {
    __builtin_amdgcn_global_load_lds(
        (const __attribute__((address_space(1))) unsigned int*)g,
        (__attribute__((address_space(3))) unsigned int*)l, 16, 0, 0);
}

// ---------------------------------------------------------------------------
// bf16 MFMA GEMM: 128x128 tile, BK=64, 4 waves (2x2), counted-vmcnt 2-buffer
// pipeline, slot-XOR swizzle (PMC-verified: 0 bank conflicts), XCD row-band
// swizzle (PMC-verified: FETCH = ideal). Round-9/10/12 text — FROZEN (PMC: t1
// 67.4-68.0 us, MfmaUtil ~19.5, VGPR 104). Do not modify.
// ---------------------------------------------------------------------------
__global__ __launch_bounds__(256) void gemm_bf16(
    const unsigned short* __restrict__ A, int ldA,
    const unsigned short* __restrict__ Wt,
    const float* __restrict__ bias, int K,
    float* __restrict__ Cf, unsigned short* __restrict__ Cb, int ldC, int colOff,
    const float* __restrict__ res, int ldRes,
    int act)
{
    __shared__ __align__(16) unsigned short Asm[2][128 * 64];
    __shared__ __align__(16) unsigned short Bsm[2][128 * 64];
    const int tid = threadIdx.x;
    const int lane = tid & 63;
    const int wv = tid >> 6;
    const int wm = wv & 1, wn = wv >> 1;
    const int quad = lane >> 4, cc = lane & 15;

    const int C = gridDim.x, R = gridDim.y;
    const int bid = blockIdx.x + C * blockIdx.y;
    const int xcd = bid & 7;
    const int s = bid >> 3;
    const int by = xcd * (R >> 3) + s / C;
    const int bx = s - (s / C) * C;
    const int row0 = by << 7;
    const int col0 = bx << 7;

    facc4 acc[4][4];
#pragma unroll
    for (int i = 0; i < 4; ++i)
#pragma unroll
        for (int j = 0; j < 4; ++j) acc[i][j] = (facc4){0.f, 0.f, 0.f, 0.f};

    const int nk = K >> 6;

    int srow[4]; int soff[4]; int sdst[4];
#pragma unroll
    for (int k = 0; k < 4; ++k) {
        int g = tid + k * 256;
        int r = g >> 3, sd = g & 7;
        srow[k] = r;
        soff[k] = (sd ^ (r & 7)) * 8;   // shorts
        sdst[k] = g * 8;                // shorts (linear LDS)
    }

    auto stage = [&](int t, int buf) {
        const int koff = t << 6;        // t*64 shorts
#pragma unroll
        for (int k = 0; k < 4; ++k) {
            async16(A  + (size_t)(row0 + srow[k]) * ldA + koff + soff[k], &Asm[buf][sdst[k]]);
            async16(Wt + (size_t)(col0 + srow[k]) * K   + koff + soff[k], &Bsm[buf][sdst[k]]);
        }
    };

    stage(0, 0);

    const int swz = cc & 7;
    int cur = 0;
    for (int t = 0; t < nk; ++t) {
        if (t + 1 < nk) {
            stage(t + 1, cur ^ 1);
            asm volatile("s_waitcnt vmcnt(8)" ::: "memory");
        } else {
            asm volatile("s_waitcnt vmcnt(0)" ::: "memory");
        }
        __builtin_amdgcn_s_barrier();
        __builtin_amdgcn_sched_barrier(0);
#pragma unroll
        for (int kk = 0; kk < 2; ++kk) {
            const int sl = ((kk * 4 + quad) ^ swz) * 8;
            bfrag8 afr[4], bfr[4];
#pragma unroll
            for (int mt = 0; mt < 4; ++mt)
                afr[mt] = *(const bfrag8*)&Asm[cur][(wm * 64 + mt * 16 + cc) * 64 + sl];
#pragma unroll
            for (int nt = 0; nt < 4; ++nt)
                bfr[nt] = *(const bfrag8*)&Bsm[cur][(wn * 64 + nt * 16 + cc) * 64 + sl];
#pragma unroll
            for (int mt = 0; mt < 4; ++mt)
#pragma unroll
                for (int nt = 0; nt < 4; ++nt)
                    acc[mt][nt] = __builtin_amdgcn_mfma_f32_16x16x32_bf16(
                        afr[mt], bfr[nt], acc[mt][nt], 0, 0, 0);
        }
        asm volatile("s_waitcnt lgkmcnt(0)" ::: "memory");
        __builtin_amdgcn_sched_barrier(0);   // rule #18 fence: nothing crosses the WAR point
        __builtin_amdgcn_s_barrier();
        cur ^= 1;
    }

#pragma unroll
    for (int nt = 0; nt < 4; ++nt) {
        int col = col0 + wn * 64 + nt * 16 + cc;
        float bvv = bias[col];
#pragma unroll
        for (int mt = 0; mt < 4; ++mt) {
            int rowb = row0 + wm * 64 + mt * 16 + quad * 4;
#pragma unroll
            for (int r = 0; r < 4; ++r) {
                float v = acc[mt][nt][r] + bvv;
                if (act == 1) v = gelu_(v);
                size_t row = (size_t)(rowb + r);
                if (res) v += res[row * ldRes + col];
                size_t idx = row * ldC + colOff + col;
                if (Cf) Cf[idx] = v;
                else    Cb[idx] = f2bf(v);
            }
        }
    }
}

// ---------------------------------------------------------------------------
// Fused prologue: phi tables + x->bf16 + ALL weight converts + bias pack in
// ONE launch. Segments:
//   [0,8192)      phi: cos/sin(pos_phases), 2097152 elems
//   [8192,12288)  xcvt: x fp32 -> XCAT left half bf16, 8/thread
//   [12288,15488) wcvt: 32x32 transpose tiles (table below)
//   [15488,15495) bias pack b_v|b_m|b_q|b_ke -> cbias (1664 floats)
// wcvt sub-table (wb = bid-12288):
//   [0,768)    w_v/w_m/w_q 512x512 -> WT + seg*262144  (contiguous 1536x512)
//   [768,832)  w_ke 512x128        -> WT + 786432
//   [832,1088) w_o  512x512        -> WT + 851968
//   [1088,1600) w_s1 1024x512      -> WT + 1114112
//   [1600,1664) w_s2 512x128       -> WT + 1638400
//   [1664,2688) w_t1 1024x1024     -> WT + 1703936
//   [2688,3200) w_t2 1024x512      -> WT + 2752512
// ---------------------------------------------------------------------------
__global__ __launch_bounds__(256) void k_prep(
    const float* __restrict__ pp, float* __restrict__ cphi, float* __restrict__ sphi,
    const float* __restrict__ x, unsigned short* __restrict__ xcat,
    const float* __restrict__ w_v, const float* __restrict__ w_m,
    const float* __restrict__ w_q, const float* __restrict__ w_o,
    const float* __restrict__ w_ke, const float* __restrict__ w_s1,
    const float* __restrict__ w_s2, const float* __restrict__ w_t1,
    const float* __restrict__ w_t2, unsigned short* __restrict__ WT,
    const float* __restrict__ b_v, const float* __restrict__ b_m,
    const float* __restrict__ b_q, const float* __restrict__ b_ke,
    float* __restrict__ cbias)
{
    const int bid = blockIdx.x;
    const int tid = threadIdx.x;
    if (bid < 8192) {
        int i = bid * 256 + tid;          // < 2097152 exactly
        float s, c;
        sincosf(pp[i], &s, &c);
        cphi[i] = c;
        sphi[i] = s;
        return;
    }
    if (bid < 12288) {
        int g = (bid - 8192) * 256 + tid; // 1,048,576 groups of 8
        int c8 = (g & 63) * 8, r = g >> 6;
        const float4* xp = (const float4*)(x + (size_t)r * 512 + c8);
        float4 a = xp[0], b = xp[1];
        uint4 o;
        o.x = (unsigned int)f2bf(a.x) | ((unsigned int)f2bf(a.y) << 16);
        o.y = (unsigned int)f2bf(a.z) | ((unsigned int)f2bf(a.w) << 16);
        o.z = (unsigned int)f2bf(b.x) | ((unsigned int)f2bf(b.y) << 16);
        o.w = (unsigned int)f2bf(b.z) | ((unsigned int)f2bf(b.w) << 16);
        *(uint4*)&xcat[(size_t)r * 1024 + c8] = o;
        return;
    }
    if (bid >= 15488) {
        int i = (bid - 15488) * 256 + tid;   // 0..1791, valid < 1664
        if (i < 512) cbias[i] = b_v[i];
        else if (i < 1024) cbias[i] = b_m[i - 512];
        else if (i < 1536) cbias[i] = b_q[i - 1024];
        else if (i < 1664) cbias[i] = b_ke[i - 1536];
        return;
    }
    const int wb = bid - 12288;
    const float* W; int K, N; unsigned short* Wt; int l;
    if (wb < 768) {
        K = 512; N = 512;
        int seg = wb >> 8; l = wb & 255;
        W = (seg == 0) ? w_v : (seg == 1) ? w_m : w_q;
        Wt = WT + seg * 262144;
    } else if (wb < 832)  { W = w_ke; K = 512;  N = 128;  Wt = WT + 786432;  l = wb - 768; }
    else if (wb < 1088)   { W = w_o;  K = 512;  N = 512;  Wt = WT + 851968;  l = wb - 832; }
    else if (wb < 1600)   { W = w_s1; K = 1024; N = 512;  Wt = WT + 1114112; l = wb - 1088; }
    else if (wb < 1664)   { W = w_s2; K = 512;  N = 128;  Wt = WT + 1638400; l = wb - 1600; }
    else if (wb < 2688)   { W = w_t1; K = 1024; N = 1024; Wt = WT + 1703936; l = wb - 1664; }
    else                  { W = w_t2; K = 1024; N = 512;  Wt = WT + 2752512; l = wb - 2688; }
    const int ntx = N >> 5;
    const int bx = l % ntx, by = l / ntx;
    __shared__ float t[32][33];
    const int tx = tid & 31, ty = tid >> 5;   // ty 0..7
#pragma unroll
    for (int r = 0; r < 4; ++r) {
        int k = by * 32 + ty + r * 8;
        t[ty + r * 8][tx] = W[(size_t)k * N + bx * 32 + tx];
    }
    __syncthreads();
#pragma unroll
    for (int r = 0; r < 4; ++r) {
        int n = bx * 32 + ty + r * 8;
        Wt[(size_t)n * K + by * 32 + tx] = f2bf(t[tx][ty + r * 8]);
    }
}

// ---------------------------------------------------------------------------
// Fused g_lin + values: one wave per row, x read ONCE coalesced.
// glin[r] = x[r,:]@w_g + b_g;  gv[r,m] = (x[r,:]@w_ve[:,m] + b_ve[m])*sigmoid(glin)
// ---------------------------------------------------------------------------
__global__ __launch_bounds__(256) void k_glinval(
    const float* __restrict__ x, const float* __restrict__ wg,
    const float* __restrict__ bg, const float* __restrict__ wve,
    const float* __restrict__ bve, float* __restrict__ glin,
    float* __restrict__ gv)
{
    int wid = threadIdx.x >> 6, lane = threadIdx.x & 63;
    int row = blockIdx.x * 4 + wid;
    const float4* xr = (const float4*)(x + (size_t)row * DDIM);
    const float4* w4 = (const float4*)wg;
    float4 a0 = xr[lane], a1 = xr[lane + 64];
    float4 w0 = w4[lane], w1 = w4[lane + 64];
    float p = a0.x * w0.x + a0.y * w0.y + a0.z * w0.z + a0.w * w0.w
            + a1.x * w1.x + a1.y * w1.y + a1.z * w1.z + a1.w * w1.w;
    float vm[8];
#pragma unroll
    for (int m = 0; m < 8; ++m) vm[m] = 0.f;
    const float4* wv4 = (const float4*)wve;
    float xa[8] = {a0.x, a0.y, a0.z, a0.w, a1.x, a1.y, a1.z, a1.w};
#pragma unroll
    for (int j = 0; j < 8; ++j) {
        int krow = (j < 4) ? (4 * lane + j) : (256 + 4 * lane + (j - 4));
        float4 wlo = wv4[krow * 2], whi = wv4[krow * 2 + 1];
        float xv = xa[j];
        vm[0] += xv * wlo.x; vm[1] += xv * wlo.y; vm[2] += xv * wlo.z; vm[3] += xv * wlo.w;
        vm[4] += xv * whi.x; vm[5] += xv * whi.y; vm[6] += xv * whi.z; vm[7] += xv * whi.w;
    }
#pragma unroll
    for (int d = 32; d >= 1; d >>= 1) {
        p += __shfl_xor(p, d, 64);
#pragma unroll
        for (int m = 0; m < 8; ++m) vm[m] += __shfl_xor(vm[m], d, 64);
    }
    if (lane == 0) {
        float gl = p + bg[0];
        glin[row] = gl;
        float sg = sigmoid_(gl);
        float* gp = gv + (size_t)row * VDIM;
#pragma unroll
        for (int m = 0; m < 8; ++m) gp[m] = (vm[m] + bve[m]) * sg;
    }
}

// ---------------------------------------------------------------------------
// scan family 1: per (b,d) cumsums of {wv*cos, wv*sin, mag, x} — 3 passes
// v1/mlin/qlin live row-interleaved in VMQ (stride 1536, offsets 0/512/1024).
// NC2=64/CL2=64 (round-10 verified optimum; NC2=128 regressed ~14 us).
// ---------------------------------------------------------------------------
__global__ __launch_bounds__(256) void k_scan1a(
    const unsigned short* __restrict__ vmq, const float* __restrict__ x,
    const float* __restrict__ cphi, const float* __restrict__ sphi,
    const float* __restrict__ msp, float* __restrict__ sum2)
{
    int g = blockIdx.x * 256 + threadIdx.x;   // B*NC2*D = 131072
    int d = g & 511;
    int rest = g >> 9;
    int chunk = rest & (NC2 - 1);
    int b = rest >> 6;
    float msabs = fabsf(msp[0]);
    size_t row = (size_t)b * LSEQ + chunk * CL2;
    const unsigned short* vp = vmq + row * VMQ_S + d;
    const float* xp = x + row * DDIM + d;
    size_t pbase = ((size_t)chunk * CL2) * DDIM + d;
    float ac = 0.f, as = 0.f, am = 0.f, ax = 0.f;
    for (int i = 0; i < CL2; ++i) {
        float vv = bf2f(vp[0]);
        float ml = bf2f(vp[512]);
        float xv = xp[0];
        float cp = cphi[pbase], sp = sphi[pbase];
        float mag = msabs * sigmoid_(ml);
        float wv = mag * vv;
        ac += wv * cp; as += wv * sp; am += mag; ax += xv;
        vp += VMQ_S; xp += DDIM; pbase += DDIM;
    }
    int col = (b * DDIM + d) * NC2 + chunk;   // [b][d][chunk]
    sum2[0 * PL2 + col] = ac;
    sum2[1 * PL2 + col] = as;
    sum2[2 * PL2 + col] = am;
    sum2[3 * PL2 + col] = ax;
}

__global__ __launch_bounds__(256) void k_scan1b(float* __restrict__ sum2)
{
    int g = blockIdx.x * 256 + threadIdx.x;   // 4*B*D = 8192 rows of NC2
    float* p = sum2 + (size_t)g * NC2;
    float run = 0.f;
    for (int i = 0; i < NC2; ++i) { float t = p[i]; p[i] = run; run += t; }
}

__global__ __launch_bounds__(256) void k_scan1c(
    const unsigned short* __restrict__ vmq, const float* __restrict__ x,
    const float* __restrict__ cphi, const float* __restrict__ sphi,
    const float* __restrict__ msp, const float* __restrict__ sum2,
    unsigned short* __restrict__ pret, unsigned short* __restrict__ xcat)
{
    int g = blockIdx.x * 256 + threadIdx.x;
    int d = g & 511;
    int rest = g >> 9;
    int chunk = rest & (NC2 - 1);
    int b = rest >> 6;
    float msabs = fabsf(msp[0]);
    int col = (b * DDIM + d) * NC2 + chunk;
    float ac = sum2[col];
    float as = sum2[PL2 + col];
    float am = sum2[2 * PL2 + col];
    float ax = sum2[3 * PL2 + col];
    size_t row = (size_t)b * LSEQ + chunk * CL2;
    const unsigned short* vp = vmq + row * VMQ_S + d;
    size_t base = row * DDIM + d;
    size_t pbase = ((size_t)chunk * CL2) * DDIM + d;
    int l = chunk * CL2;
    const float rsd = 0.04419417382415922f;   // 1/sqrt(512)
    for (int i = 0; i < CL2; ++i, ++l) {
        float vv = bf2f(vp[0]);
        float ml = bf2f(vp[512]);
        float q = bf2f(vp[1024]);
        float xv = x[base];
        float cp = cphi[pbase], sp = sphi[pbase];
        float mag = msabs * sigmoid_(ml);
        float wv = mag * vv;
        ac += wv * cp; as += wv * sp; am += mag; ax += xv;
        float inv = rsqrtf(am + 1e-8f);
        float mc = ac * inv, msn = as * inv;
        float cq, sq;
        sincosf(q, &sq, &cq);
        float cpq = cp * cq - sp * sq;   // cos(phi+q)
        float spq = sp * cq + cp * sq;   // sin(phi+q)
        pret[base] = f2bf((mc * cpq + msn * spq) * rsd);
        size_t orow = (size_t)b * LSEQ + l;
        xcat[orow * 1024 + 512 + d] = f2bf(ax / (float)(l + 1));
        vp += VMQ_S; base += DDIM; pbase += DDIM;
    }
}

// ---------------------------------------------------------------------------
// phase tables (bf16): storage_phase (from sk fp32) and query_phase (ke bf16)
// ---------------------------------------------------------------------------
__global__ void k_phases(const float* __restrict__ sk, const unsigned short* __restrict__ ke,
                         unsigned short* __restrict__ csp, unsigned short* __restrict__ ssp,
                         unsigned short* __restrict__ cqp, unsigned short* __restrict__ sqp, int n)
{
    int g = blockIdx.x * 256 + threadIdx.x;
    if (g < n) {
        float s, c;
        float spv = tanhf(sk[g]) * PI_F;
        sincosf(spv, &s, &c);
        csp[g] = f2bf(c); ssp[g] = f2bf(s);
        float qpv = tanhf(bf2f(ke[g])) * PI_F;
        sincosf(qpv, &s, &c);
        cqp[g] = f2bf(c); sqp[g] = f2bf(s);
    }
}

// ---------------------------------------------------------------------------
// gate cumsum per batch: block-parallel scan of sigmoid(g_lin) over L=4096
// ---------------------------------------------------------------------------
__global__ __launch_bounds__(1024) void k_gatescan(const float* __restrict__ glin,
                                                   float* __restrict__ gcum)
{
    __shared__ float s[1024];
    int b = blockIdx.x, tid = threadIdx.x;
    const float* gp = glin + (size_t)b * LSEQ + tid * 4;
    float e0 = sigmoid_(gp[0]);
    float e1 = sigmoid_(gp[1]);
    float e2 = sigmoid_(gp[2]);
    float e3 = sigmoid_(gp[3]);
    float l0 = e0, l1 = l0 + e1, l2 = l1 + e2, l3 = l2 + e3;
    s[tid] = l3;
    __syncthreads();
    for (int off = 1; off < 1024; off <<= 1) {
        float t = (tid >= off) ? s[tid - off] : 0.0f;
        __syncthreads();
        s[tid] += t;
        __syncthreads();
    }
    float excl = s[tid] - l3;
    float* out = gcum + (size_t)b * LSEQ + tid * 4;
    out[0] = excl + l0; out[1] = excl + l1; out[2] = excl + l2; out[3] = excl + l3;
}

// ---------------------------------------------------------------------------
// kv scan: state (P,V) per batch. Block = (b, chunk). Wave w owns v in
// {2w,2w+1}; lane owns 4 consecutive p. sum3 layout: [b][p][v][cs][chunk].
// NC3=128/CL3=32 (round-10 verified optimum). Phase tables bf16.
// ---------------------------------------------------------------------------
__device__ __forceinline__ size_t kv_sum_idx(int b, int p, int v) {
    return ((((size_t)b * PDIM + p) * VDIM + v) * 2) * NC3;
}

__global__ __launch_bounds__(256) void k_kv1(const unsigned short* __restrict__ csp,
                                             const unsigned short* __restrict__ ssp,
                                             const float* __restrict__ gv,
                                             float* __restrict__ sum3)
{
    int blk = blockIdx.x;                 // B*NC3 = 512
    int chunk = blk & (NC3 - 1), b = blk >> 7;
    int tid = threadIdx.x;
    int w = tid >> 6, lane = tid & 63;
    int v = 2 * w + (lane & 1);
    int pq = lane >> 1;                   // 0..31
    float sc[4] = {0, 0, 0, 0}, ss[4] = {0, 0, 0, 0};
    const uint2* c2p = (const uint2*)csp;
    const uint2* s2p = (const uint2*)ssp;
    int t = b * LSEQ + chunk * CL3;
    for (int i = 0; i < CL3; ++i, ++t) {
        uint2 cu = c2p[(size_t)t * 32 + pq];
        uint2 su = s2p[(size_t)t * 32 + pq];
        float g = gv[(size_t)t * VDIM + v];
        sc[0] += bflo(cu.x) * g; sc[1] += bfhi(cu.x) * g;
        sc[2] += bflo(cu.y) * g; sc[3] += bfhi(cu.y) * g;
        ss[0] += bflo(su.x) * g; ss[1] += bfhi(su.x) * g;
        ss[2] += bflo(su.y) * g; ss[3] += bfhi(su.y) * g;
    }
#pragma unroll
    for (int j = 0; j < 4; ++j) {
        size_t base = kv_sum_idx(b, pq * 4 + j, v) + chunk;
        sum3[base] = sc[j];
        sum3[base + NC3] = ss[j];
    }
}

__global__ __launch_bounds__(256) void k_kv2(float* __restrict__ sum3)
{
    int g = blockIdx.x * 256 + threadIdx.x;   // B*P*V*2 = 8192 rows
    float* p = sum3 + (size_t)g * NC3;
    float run = 0.f;
    for (int i = 0; i < NC3; ++i) { float t = p[i]; p[i] = run; run += t; }
}

__global__ __launch_bounds__(256) void k_kv3(const unsigned short* __restrict__ csp,
                                             const unsigned short* __restrict__ ssp,
                                             const unsigned short* __restrict__ cqp,
                                             const unsigned short* __restrict__ sqp,
                                             const float* __restrict__ gv,
                                             const float* __restrict__ gcum,
                                             const float* __restrict__ sum3,
                                             float* __restrict__ kvr)
{
    int blk = blockIdx.x;
    int chunk = blk & (NC3 - 1), b = blk >> 7;
    int tid = threadIdx.x;
    int w = tid >> 6, lane = tid & 63;
    int v = 2 * w + (lane & 1);
    int pq = lane >> 1;
    float sc[4], ss[4];
#pragma unroll
    for (int j = 0; j < 4; ++j) {
        size_t base = kv_sum_idx(b, pq * 4 + j, v) + chunk;
        sc[j] = sum3[base];
        ss[j] = sum3[base + NC3];
    }
    const uint2* c2p = (const uint2*)csp;
    const uint2* s2p = (const uint2*)ssp;
    const uint2* cq2p = (const uint2*)cqp;
    const uint2* sq2p = (const uint2*)sqp;
    const float rsp = 0.08838834764831845f;   // 1/sqrt(128)
    int t = b * LSEQ + chunk * CL3;
    for (int i = 0; i < CL3; ++i, ++t) {
        uint2 cu = c2p[(size_t)t * 32 + pq];
        uint2 su = s2p[(size_t)t * 32 + pq];
        float g = gv[(size_t)t * VDIM + v];
        sc[0] += bflo(cu.x) * g; sc[1] += bfhi(cu.x) * g;
        sc[2] += bflo(cu.y) * g; sc[3] += bfhi(cu.y) * g;
        ss[0] += bflo(su.x) * g; ss[1] += bfhi(su.x) * g;
        ss[2] += bflo(su.y) * g; ss[3] += bfhi(su.y) * g;
        uint2 qcu = cq2p[(size_t)t * 32 + pq];
        uint2 qsu = sq2p[(size_t)t * 32 + pq];
        float part = bflo(qcu.x) * sc[0] + bfhi(qcu.x) * sc[1]
                   + bflo(qcu.y) * sc[2] + bfhi(qcu.y) * sc[3]
                   + bflo(qsu.x) * ss[0] + bfhi(qsu.x) * ss[1]
                   + bflo(qsu.y) * ss[2] + bfhi(qsu.y) * ss[3];
        part += __shfl_down(part, 32, 64);
        part += __shfl_down(part, 16, 64);
        part += __shfl_down(part, 8, 64);
        part += __shfl_down(part, 4, 64);
        part += __shfl_down(part, 2, 64);
        if (lane < 2) {
            float gc = gcum[t];
            float scale = rsqrtf(fmaxf(gc, 1.0f)) * rsp;
            kvr[(size_t)t * VDIM + v] = part * scale;
        }
    }
}

// ---------------------------------------------------------------------------
// Fused kv_out + LayerNorm: one wave per row. Reads COMB left half (written
// by o-gemm), computes right half = kvr@w_kv + b_kv in-register, LayerNorms
// the full 1024 row, writes both halves bf16 in place.
// ---------------------------------------------------------------------------
__global__ __launch_bounds__(256) void k_kvln(unsigned short* __restrict__ comb,
                                              const float* __restrict__ kvr,
                                              const float* __restrict__ wkv,
                                              const float* __restrict__ bkv,
                                              const float* __restrict__ gam,
                                              const float* __restrict__ bet)
{
    int wid = threadIdx.x >> 6, lane = threadIdx.x & 63;
    int row = blockIdx.x * 4 + wid;
    unsigned int* rp = (unsigned int*)(comb + (size_t)row * 1024);
    // left half: 8 bf16 at cols [8*lane, 8*lane+8)
    uint4 uL = *(uint4*)&rp[lane * 4];
    float vl[8];
    vl[0] = bflo(uL.x); vl[1] = bfhi(uL.x); vl[2] = bflo(uL.y); vl[3] = bfhi(uL.y);
    vl[4] = bflo(uL.z); vl[5] = bfhi(uL.z); vl[6] = bflo(uL.w); vl[7] = bfhi(uL.w);
    // right half: kvout for wkv cols [8*lane, 8*lane+8)
    const float* kr = kvr + (size_t)row * VDIM;
    float k0 = kr[0], k1 = kr[1], k2 = kr[2], k3 = kr[3];
    float k4 = kr[4], k5 = kr[5], k6 = kr[6], k7 = kr[7];
    int c0 = lane * 8;
    float vr[8];
#pragma unroll
    for (int j = 0; j < 8; ++j) {
        int c = c0 + j;
        vr[j] = bkv[c]
              + k0 * wkv[0 * DDIM + c] + k1 * wkv[1 * DDIM + c]
              + k2 * wkv[2 * DDIM + c] + k3 * wkv[3 * DDIM + c]
              + k4 * wkv[4 * DDIM + c] + k5 * wkv[5 * DDIM + c]
              + k6 * wkv[6 * DDIM + c] + k7 * wkv[7 * DDIM + c];
    }
    float s = 0.f, s2 = 0.f;
#pragma unroll
    for (int j = 0; j < 8; ++j) {
        s += vl[j] + vr[j];
        s2 += vl[j] * vl[j] + vr[j] * vr[j];
    }
    for (int m = 32; m >= 1; m >>= 1) {
        s += __shfl_xor(s, m, 64);
        s2 += __shfl_xor(s2, m, 64);
    }
    float mu = s * (1.0f / 1024.0f);
    float var = s2 * (1.0f / 1024.0f) - mu * mu;
    float inv = rsqrtf(var + 1e-5f);
    unsigned int oL[4], oR[4];
#pragma unroll
    for (int jj = 0; jj < 4; ++jj) {
        float l0 = (vl[2 * jj] - mu) * inv * gam[c0 + 2 * jj] + bet[c0 + 2 * jj];
        float l1 = (vl[2 * jj + 1] - mu) * inv * gam[c0 + 2 * jj + 1] + bet[c0 + 2 * jj + 1];
        oL[jj] = (unsigned int)f2bf(l0) | ((unsigned int)f2bf(l1) << 16);
        int rc = 512 + c0 + 2 * jj;
        float r0 = (vr[2 * jj] - mu) * inv * gam[rc] + bet[rc];
        float r1 = (vr[2 * jj + 1] - mu) * inv * gam[rc + 1] + bet[rc + 1];
        oR[jj] = (unsigned int)f2bf(r0) | ((unsigned int)f2bf(r1) << 16);
    }
    *(uint4*)&rp[lane * 4] = make_uint4(oL[0], oL[1], oL[2], oL[3]);
    *(uint4*)&rp[256 + lane * 4] = make_uint4(oR[0], oR[1], oR[2], oR[3]);
}

// ---------------------------------------------------------------------------
extern "C" void kernel_launch(void* const* d_in, const int* in_sizes, int n_in,
                              void* d_out, int out_size, void* d_ws, size_t ws_size,
                              hipStream_t stream)
{
    const float* x    = (const float*)d_in[0];
    const float* pp   = (const float*)d_in[1];
    const float* msp  = (const float*)d_in[2];
    const float* w_v  = (const float*)d_in[3];
    const float* b_v  = (const float*)d_in[4];
    const float* w_o  = (const float*)d_in[5];
    const float* b_o  = (const float*)d_in[6];
    const float* w_m  = (const float*)d_in[7];
    const float* b_m  = (const float*)d_in[8];
    const float* w_q  = (const float*)d_in[9];
    const float* b_q  = (const float*)d_in[10];
    const float* w_ke = (const float*)d_in[11];
    const float* b_ke = (const float*)d_in[12];
    const float* w_ve = (const float*)d_in[13];
    const float* b_ve = (const float*)d_in[14];
    const float* w_s1 = (const float*)d_in[15];
    const float* b_s1 = (const float*)d_in[16];
    const float* w_s2 = (const float*)d_in[17];
    const float* b_s2 = (const float*)d_in[18];
    const float* w_g  = (const float*)d_in[19];
    const float* b_g  = (const float*)d_in[20];
    const float* w_kv = (const float*)d_in[21];
    const float* b_kv = (const float*)d_in[22];
    const float* ln_g = (const float*)d_in[23];
    const float* ln_b = (const float*)d_in[24];
    const float* w_t1 = (const float*)d_in[25];
    const float* b_t1 = (const float*)d_in[26];
    const float* w_t2 = (const float*)d_in[27];
    const float* b_t2 = (const float*)d_in[28];
    float* out = (float*)d_out;
    float* ws = (float*)d_ws;
    (void)ws_size; (void)n_in; (void)in_sizes; (void)out_size;

    // ---- workspace layout (float offsets) — round-10 layout
    unsigned short* VMQ    = (unsigned short*)(ws);              // N*1536 bf16 [dead after scan1c]
    float*          SKf    = ws + 4194304;                       // N*P fp32, inside dead VMQ region [alive step4->5]
    unsigned short* CSP    = (unsigned short*)(ws + 8388608);    // 4 bf16 phase tables reuse VMQ upper part
    unsigned short* SSP    = CSP + 2097152;
    unsigned short* CQP    = CSP + 2 * 2097152;
    unsigned short* SQP    = CSP + 3 * 2097152;
    unsigned short* KEbf   = (unsigned short*)(ws + 12582912);   // N*P bf16
    float* GVb   = ws + 13631488;                                // N*V
    float* GLINb = ws + 13762560;                                // N
    float* GCUMb = ws + 13778944;                                // N
    float* SUM2b = ws + 13795328;                                // 4*PL2 = 524288
    float* CBIAS = SUM2b;                                        // 1664 floats, live only until VMQ gemm done
    float* SUM3b = ws + 14319616;                                // 1048576
    float* KVRb  = ws + 15368192;                                // N*V
    float* CPHIb = ws + 15499264;                                // L*D fp32 [dead after scan1c]
    float* SPHIb = ws + 17596416;                                // L*D fp32 [dead after scan1c]
    unsigned short* HSbf   = (unsigned short*)(ws + 15499264);   // N*D bf16, reuses CPHI+SPHI (written step 4)
    unsigned short* PRETbf = (unsigned short*)(ws + 19693568);   // N*D bf16 [dead after o-gemm]
    unsigned short* XCAT   = (unsigned short*)(ws + 23887872);   // N*1024 bf16 [dead after s1]
    unsigned short* COMBbf = XCAT;                               // N*1024 bf16, reuses XCAT
    unsigned short* HTbf   = (unsigned short*)(ws);              // N*1024 bf16, reuses VMQ/SK
    unsigned short* WT     = (unsigned short*)(ws + 32276480);
    unsigned short* wv_t  = WT;                  // [wv|wm|wq] contiguous: 1536 x 512
    unsigned short* wke_t = WT + 786432;         // 128x512
    unsigned short* wo_t  = WT + 851968;         // 512x512
    unsigned short* ws1_t = WT + 1114112;        // 512x1024
    unsigned short* ws2_t = WT + 1638400;        // 128x512
    unsigned short* wt1_t = WT + 1703936;        // 1024x1024
    unsigned short* wt2_t = WT + 2752512;        // 512x1024

    // 1. fused prologue: phi tables + x conversion + all weight converts + bias
    k_prep<<<15495, 256, 0, stream>>>(pp, CPHIb, SPHIb, x, XCAT,
                                      w_v, w_m, w_q, w_o, w_ke, w_s1, w_s2,
                                      w_t1, w_t2, WT, b_v, b_m, b_q, b_ke, CBIAS);

    // 2. token GEMMs on x. V/M/Q fused (N=1536); KE separate.
    gemm_bf16<<<dim3(12, 128), 256, 0, stream>>>(XCAT, 1024, wv_t, CBIAS, 512, nullptr, VMQ, VMQ_S, 0, nullptr, 0, 0);
    gemm_bf16<<<dim3(1, 128), 256, 0, stream>>>(XCAT, 1024, wke_t, b_ke, 512, nullptr, KEbf, 128, 0, nullptr, 0, 0);
    k_glinval<<<4096, 256, 0, stream>>>(x, w_g, b_g, w_ve, b_ve, GLINb, GVb);

    // 3. (b,d) scans -> pos_ret (bf16), context_avg (bf16 into XCAT right half)
    k_scan1a<<<512, 256, 0, stream>>>(VMQ, x, CPHIb, SPHIb, msp, SUM2b);
    k_scan1b<<<32, 256, 0, stream>>>(SUM2b);
    k_scan1c<<<512, 256, 0, stream>>>(VMQ, x, CPHIb, SPHIb, msp, SUM2b, PRETbf, XCAT);

    // 4. storage-key branch: s1 (XCAT) -> gelu -> bf16 hs; s2 -> fp32 sk
    gemm_bf16<<<dim3(4, 128), 256, 0, stream>>>(XCAT, 1024, ws1_t, b_s1, 1024, nullptr, HSbf, 512, 0, nullptr, 0, 1);
    gemm_bf16<<<dim3(1, 128), 256, 0, stream>>>(HSbf, 512, ws2_t, b_s2, 512, SKf, nullptr, 128, 0, nullptr, 0, 0);

    // 5. phase tables (bf16) for storage/query; gate cumsum
    k_phases<<<8192, 256, 0, stream>>>(SKf, KEbf, CSP, SSP, CQP, SQP, 2097152);
    k_gatescan<<<4, 1024, 0, stream>>>(GLINb, GCUMb);

    // 6. kv scan -> kv_retrieved (fp32)
    k_kv1<<<512, 256, 0, stream>>>(CSP, SSP, GVb, SUM3b);
    k_kv2<<<32, 256, 0, stream>>>(SUM3b);
    k_kv3<<<512, 256, 0, stream>>>(CSP, SSP, CQP, SQP, GVb, GCUMb, SUM3b, KVRb);

    // 7. heads into combined (bf16), fused kvout+LN, MLP (bf16), residual fp32
    gemm_bf16<<<dim3(4, 128), 256, 0, stream>>>(PRETbf, 512, wo_t, b_o, 512, nullptr, COMBbf, 1024, 0, nullptr, 0, 0);
    k_kvln<<<4096, 256, 0, stream>>>(COMBbf, KVRb, w_kv, b_kv, ln_g, ln_b);
    gemm_bf16<<<dim3(8, 128), 256, 0, stream>>>(COMBbf, 1024, wt1_t, b_t1, 1024, nullptr, HTbf, 1024, 0, nullptr, 0, 1);
    gemm_bf16<<<dim3(4, 128), 256, 0, stream>>>(HTbf, 1024, wt2_t, b_t2, 1024, out, nullptr, 512, 0, x, 512, 0);
}